// Round 1
// 640.433 us; speedup vs baseline: 1.1931x; 1.1931x over previous
//
#include <hip/hip_runtime.h>
#include <math.h>

#define N_NODESC 100000
#define N_EDGESC 1600000
#define DIMC 128
#define EPSV 1e-12f

typedef __attribute__((ext_vector_type(8))) short short8;
typedef __attribute__((ext_vector_type(4))) float f32x4;

// ---- bf16 helpers (round-to-nearest-even), packed 2 per uint ----
__device__ inline unsigned bf16r(float f) {
    unsigned u = __float_as_uint(f);
    return (u + 0x7FFFu + ((u >> 16) & 1u)) >> 16;
}
__device__ inline unsigned pack2(float lo, float hi) {
    return bf16r(lo) | (bf16r(hi) << 16);
}
__device__ inline float unlo(unsigned u) { return __uint_as_float(u << 16); }
__device__ inline float unhi(unsigned u) { return __uint_as_float(u & 0xFFFF0000u); }

// split f into hi/lo bf16 parts: f ~= hi + lo, |err| ~ 2^-17 * |f|
__device__ inline void bfsplit(float f, unsigned& h, unsigned& l) {
    h = bf16r(f);
    float fh = __uint_as_float(h << 16);
    l = bf16r(f - fh);
}

// ---------------- per-node pretransform -> interleaved bf16 gather table,
// with edge histogram fused in (25000 blocks x 64 edges = 1.6M exactly).
__global__ void pretransform_k(const float* __restrict__ e_emb,
                               const float* __restrict__ b_emb,
                               const float* __restrict__ s_emb,
                               const int* __restrict__ dst,
                               unsigned* __restrict__ tab,
                               int* __restrict__ deg) {
    // fused histogram: fire-and-forget atomics, no dependency on node work
    {
        int e = blockIdx.x * 64 + threadIdx.x;
        if (threadIdx.x < 64 && e < N_EDGESC) atomicAdd(&deg[dst[e]], 1);
    }
    int wave = (blockIdx.x * blockDim.x + threadIdx.x) >> 6;
    int lane = threadIdx.x & 63;
    if (wave >= N_NODESC) return;
    float2 ev = ((const float2*)(e_emb + (size_t)wave * DIMC))[lane];
    float2 bv = ((const float2*)(b_emb + (size_t)wave * DIMC))[lane];
    float2 sv = ((const float2*)(s_emb + (size_t)wave * DIMC))[lane];
    float bss = bv.x * bv.x + bv.y * bv.y;
    float sss = sv.x * sv.x + sv.y * sv.y;
    #pragma unroll
    for (int m = 1; m < 64; m <<= 1) {
        bss += __shfl_xor(bss, m, 64);
        sss += __shfl_xor(sss, m, 64);
    }
    float bn  = sqrtf(bss);
    float bns = fmaxf(bn, EPSV);
    float bcl = fminf(fmaxf(bns, EPSV), 1.0f - 1e-5f);
    float bsc = atanhf(bcl) / bns;
    float sn  = sqrtf(sss);
    float ssc = 1.0f / fmaxf(sn, EPSV);
    unsigned* p = tab + (size_t)wave * 192 + lane * 3;
    uint3 v;
    v.x = pack2(ev.x, ev.y);
    v.y = pack2(bv.x * bsc, bv.y * bsc);
    v.z = pack2(sv.x * ssc, sv.y * ssc);
    *(uint3*)p = v;
}

// ---------------- CSR build: two-level scan, fill
__global__ void scan1_k(const int* __restrict__ deg, int* __restrict__ scanned,
                        int* __restrict__ partials) {
    __shared__ int s[256];
    int t = threadIdx.x;
    int g = blockIdx.x * 256 + t;
    int v = (g < N_NODESC) ? deg[g] : 0;
    s[t] = v;
    __syncthreads();
    for (int off = 1; off < 256; off <<= 1) {
        int x = (t >= off) ? s[t - off] : 0;
        __syncthreads();
        s[t] += x;
        __syncthreads();
    }
    if (g < N_NODESC) scanned[g] = s[t];
    if (t == 255) partials[blockIdx.x] = s[255];
}

__global__ void scan2_k(const int* __restrict__ partials, int* __restrict__ blockoff, int nb) {
    __shared__ int s[512];
    int t = threadIdx.x;
    int v = (t < nb) ? partials[t] : 0;
    s[t] = v;
    __syncthreads();
    for (int off = 1; off < 512; off <<= 1) {
        int x = (t >= off) ? s[t - off] : 0;
        __syncthreads();
        s[t] += x;
        __syncthreads();
    }
    if (t < nb) blockoff[t] = s[t] - v;  // exclusive
}

__global__ void scan3_k(const int* __restrict__ scanned, const int* __restrict__ blockoff,
                        int* __restrict__ offs) {
    int g = blockIdx.x * 256 + threadIdx.x;
    if (g < N_NODESC) offs[g + 1] = scanned[g] + blockoff[blockIdx.x];
    if (g == 0) offs[0] = 0;
}

__global__ void fill_k(const int* __restrict__ src, const int* __restrict__ dst,
                       const int* __restrict__ offs, int* __restrict__ cursor,
                       int* __restrict__ esrc) {
    int e = blockIdx.x * 256 + threadIdx.x;
    if (e < N_EDGESC) {
        int d = dst[e];
        int pos = offs[d] + atomicAdd(&cursor[d], 1);
        esrc[pos] = src[e];
    }
}

// ---------------- aggregation: one wave per node, gather bf16 interleaved table.
// 4-edge unroll => 4 independent 12B gathers + 4 esrc loads in flight per iter
// (was 2); VGPR_Count was 16, so MLP is free. Accumulate fp32.
__global__ void aggregate_k(const unsigned* __restrict__ tab,
                            const int* __restrict__ offs,
                            const int* __restrict__ esrc,
                            float* __restrict__ out) {
    int wave = (blockIdx.x * blockDim.x + threadIdx.x) >> 6;
    int lane = threadIdx.x & 63;
    if (wave >= N_NODESC) return;
    int beg = offs[wave], end = offs[wave + 1];
    float ae0 = 0.f, ae1 = 0.f, ab0 = 0.f, ab1 = 0.f, as0 = 0.f, as1 = 0.f;
    int lo3 = lane * 3;
    int j = beg;
    for (; j + 3 < end; j += 4) {
        int s0 = __builtin_nontemporal_load(esrc + j);
        int s1 = __builtin_nontemporal_load(esrc + j + 1);
        int s2 = __builtin_nontemporal_load(esrc + j + 2);
        int s3 = __builtin_nontemporal_load(esrc + j + 3);
        uint3 v0 = *(const uint3*)(tab + (size_t)s0 * 192 + lo3);
        uint3 v1 = *(const uint3*)(tab + (size_t)s1 * 192 + lo3);
        uint3 v2 = *(const uint3*)(tab + (size_t)s2 * 192 + lo3);
        uint3 v3 = *(const uint3*)(tab + (size_t)s3 * 192 + lo3);
        ae0 += (unlo(v0.x) + unlo(v1.x)) + (unlo(v2.x) + unlo(v3.x));
        ae1 += (unhi(v0.x) + unhi(v1.x)) + (unhi(v2.x) + unhi(v3.x));
        ab0 += (unlo(v0.y) + unlo(v1.y)) + (unlo(v2.y) + unlo(v3.y));
        ab1 += (unhi(v0.y) + unhi(v1.y)) + (unhi(v2.y) + unhi(v3.y));
        as0 += (unlo(v0.z) + unlo(v1.z)) + (unlo(v2.z) + unlo(v3.z));
        as1 += (unhi(v0.z) + unhi(v1.z)) + (unhi(v2.z) + unhi(v3.z));
    }
    for (; j < end; ++j) {
        int s0 = __builtin_nontemporal_load(esrc + j);
        uint3 v0 = *(const uint3*)(tab + (size_t)s0 * 192 + lo3);
        ae0 += unlo(v0.x); ae1 += unhi(v0.x);
        ab0 += unlo(v0.y); ab1 += unhi(v0.y);
        as0 += unlo(v0.z); as1 += unhi(v0.z);
    }
    int deg = end - beg;
    float inv = (deg > 0) ? 1.0f / (float)deg : 0.0f;
    ((float2*)(out + (size_t)wave * DIMC))[lane]                           = make_float2(ae0 * inv, ae1 * inv);
    ((float2*)(out + (size_t)(N_NODESC + wave) * DIMC))[lane]              = make_float2(ab0 * inv, ab1 * inv);
    ((float2*)(out + (size_t)(2 * (size_t)N_NODESC + wave) * DIMC))[lane]  = make_float2(as0 * inv, as1 * inv);
}

// ---------------- fused GEMM via MFMA with bf16 hi/lo split (fp32-accurate):
// C = A@W^T + b, A fp32 in-place in `out`. Per product: Ah*Wh + Al*Wh + Ah*Wl,
// error ~2^-17 relative -> numerically equivalent to the fp32 VALU version,
// but runs on the matrix pipe instead of saturating VALU issue.
// Block: 256 thr = 4 waves, tile 64 rows x 128 cols, K split in 2 halves of 64.
// W staged per-half in LDS as bf16 hi/lo, [128][72] pad (144B row = 16B-aligned,
// 2-way bank alias only).
__global__ __launch_bounds__(256, 2) void gemm_mfma_k(
    float* __restrict__ out,
    const float* __restrict__ W_e, const float* __restrict__ b_e,
    const float* __restrict__ W_b, const float* __restrict__ b_b,
    const float* __restrict__ W_s, const float* __restrict__ b_s,
    const int* __restrict__ deg) {
    __shared__ unsigned short Wh[128][72];
    __shared__ unsigned short Wl[128][72];
    int c = blockIdx.y;
    const float* W    = (c == 0) ? W_e : (c == 1) ? W_b : W_s;
    const float* bias = (c == 0) ? b_e : (c == 1) ? b_b : b_s;
    float* A = out + (size_t)c * N_NODESC * DIMC;

    int tid = threadIdx.x;
    int wid = tid >> 6, lane = tid & 63;
    int m0 = blockIdx.x * 64;
    // A-fragment addressing: row = lane&15, k-chunk by lane>>4 (8 contiguous k).
    int arow = m0 + wid * 16 + (lane & 15);
    int kb = (lane >> 4) * 8;
    bool rowok = (arow < N_NODESC);
    const float* Ap = A + (size_t)arow * DIMC + kb;
    int colw = lane & 15;

    f32x4 acc[8] = {};

    for (int h = 0; h < 2; ++h) {
        // ---- A fragments for this K-half (global -> reg, fp32 -> bf16 hi/lo)
        short8 Ah[2], Al[2];
        #pragma unroll
        for (int ks = 0; ks < 2; ++ks) {
            float4 a0 = make_float4(0.f, 0.f, 0.f, 0.f);
            float4 a1 = a0;
            if (rowok) {
                a0 = *(const float4*)(Ap + h * 64 + ks * 32);
                a1 = *(const float4*)(Ap + h * 64 + ks * 32 + 4);
            }
            #define SPLIT8(val, idx) { unsigned hh, ll; bfsplit(val, hh, ll); \
                Ah[ks][idx] = (short)hh; Al[ks][idx] = (short)ll; }
            SPLIT8(a0.x, 0) SPLIT8(a0.y, 1) SPLIT8(a0.z, 2) SPLIT8(a0.w, 3)
            SPLIT8(a1.x, 4) SPLIT8(a1.y, 5) SPLIT8(a1.z, 6) SPLIT8(a1.w, 7)
            #undef SPLIT8
        }
        // ---- stage W K-half into LDS as hi/lo bf16
        if (h) __syncthreads();   // previous half's reads done before overwrite
        #pragma unroll
        for (int r = 0; r < 8; ++r) {
            int flat = (r * 256 + tid) * 4;      // float index within half
            int n  = flat >> 6;                  // 64 floats per row-half
            int kk = flat & 63;
            float4 w4 = *(const float4*)(W + (size_t)n * DIMC + h * 64 + kk);
            unsigned h0, h1, h2, h3, l0, l1, l2, l3;
            bfsplit(w4.x, h0, l0); bfsplit(w4.y, h1, l1);
            bfsplit(w4.z, h2, l2); bfsplit(w4.w, h3, l3);
            *(uint2*)&Wh[n][kk] = make_uint2(h0 | (h1 << 16), h2 | (h3 << 16));
            *(uint2*)&Wl[n][kk] = make_uint2(l0 | (l1 << 16), l2 | (l3 << 16));
        }
        __syncthreads();
        // ---- MFMA: 8 col-groups x 2 k-steps x 3 split terms
        #pragma unroll
        for (int n = 0; n < 8; ++n) {
            int col = n * 16 + colw;
            #pragma unroll
            for (int ks = 0; ks < 2; ++ks) {
                short8 wh = *(const short8*)&Wh[col][ks * 32 + kb];
                short8 wl = *(const short8*)&Wl[col][ks * 32 + kb];
                acc[n] = __builtin_amdgcn_mfma_f32_16x16x32_bf16(Ah[ks], wh, acc[n], 0, 0, 0);
                acc[n] = __builtin_amdgcn_mfma_f32_16x16x32_bf16(Al[ks], wh, acc[n], 0, 0, 0);
                acc[n] = __builtin_amdgcn_mfma_f32_16x16x32_bf16(Ah[ks], wl, acc[n], 0, 0, 0);
            }
        }
    }

    // ---- epilogue. C/D layout: col = lane&15 (within n-group), row = (lane>>4)*4 + reg
    int r0 = m0 + wid * 16 + (lane >> 4) * 4;
    float bn[8];
    #pragma unroll
    for (int n = 0; n < 8; ++n) bn[n] = bias[n * 16 + colw];

    if (c == 0) {
        #pragma unroll
        for (int rg = 0; rg < 4; ++rg) {
            int row = r0 + rg;
            if (row >= N_NODESC) continue;
            float* Ar = A + (size_t)row * DIMC;
            #pragma unroll
            for (int n = 0; n < 8; ++n) {
                float z = acc[n][rg] + bn[n];
                Ar[n * 16 + colw] = (z >= 0.f) ? z : 0.2f * z;
            }
        }
    } else {
        #pragma unroll
        for (int rg = 0; rg < 4; ++rg) {
            float z[8];
            float ss = 0.f;
            #pragma unroll
            for (int n = 0; n < 8; ++n) {
                z[n] = acc[n][rg] + bn[n];
                ss += z[n] * z[n];
            }
            // row's 128 cols live in the 16 lanes sharing lane>>4: reduce over bits 0..3
            ss += __shfl_xor(ss, 1, 64);
            ss += __shfl_xor(ss, 2, 64);
            ss += __shfl_xor(ss, 4, 64);
            ss += __shfl_xor(ss, 8, 64);
            float nrm = sqrtf(ss);
            float scale;
            if (c == 1) {
                float nsafe = fmaxf(nrm, EPSV);
                scale = tanhf(nsafe) / nsafe;       // expmap0
            } else {
                scale = 1.0f / fmaxf(nrm, EPSV);    // l2_normalize
            }
            int row = r0 + rg;
            if (row < N_NODESC) {
                if (deg[row] <= 0) scale = 0.0f;
                float* Ar = A + (size_t)row * DIMC;
                #pragma unroll
                for (int n = 0; n < 8; ++n) Ar[n * 16 + colw] = z[n] * scale;
            }
        }
    }
}

extern "C" void kernel_launch(void* const* d_in, const int* in_sizes, int n_in,
                              void* d_out, int out_size, void* d_ws, size_t ws_size,
                              hipStream_t stream) {
    const float* e_emb = (const float*)d_in[0];
    const float* b_emb = (const float*)d_in[1];
    const float* s_emb = (const float*)d_in[2];
    const float* W_e   = (const float*)d_in[3];
    const float* b_e   = (const float*)d_in[4];
    const float* W_b   = (const float*)d_in[5];
    const float* b_b   = (const float*)d_in[6];
    const float* W_s   = (const float*)d_in[7];
    const float* b_s   = (const float*)d_in[8];
    const int*   src   = (const int*)d_in[9];
    const int*   dst   = (const int*)d_in[10];
    float* out = (float*)d_out;

    // workspace layout
    char* w = (char*)d_ws;
    unsigned* tab = (unsigned*)w; w += (size_t)N_NODESC * 192 * sizeof(unsigned);  // 76.8 MB
    int* deg      = (int*)w;   w += (size_t)N_NODESC * sizeof(int);
    int* cursor   = (int*)w;   w += (size_t)N_NODESC * sizeof(int);
    int* scanned  = (int*)w;   w += (size_t)N_NODESC * sizeof(int);
    int* partials = (int*)w;   w += 512 * sizeof(int);
    int* blockoff = (int*)w;   w += 512 * sizeof(int);
    int* offs     = (int*)w;   w += (size_t)(N_NODESC + 1) * sizeof(int);
    w = (char*)(((uintptr_t)w + 255) & ~(uintptr_t)255);
    int* esrc     = (int*)w;   w += (size_t)N_EDGESC * sizeof(int);

    const int nbScan  = (N_NODESC + 255) / 256;   // 391
    const int nbEdge  = (N_EDGESC + 255) / 256;   // 6250
    const int nbNode4 = (N_NODESC + 3) / 4;       // 25000
    const int nbTile  = (N_NODESC + 63) / 64;     // 1563

    hipMemsetAsync(deg, 0, (size_t)2 * N_NODESC * sizeof(int), stream);

    pretransform_k<<<nbNode4, 256, 0, stream>>>(e_emb, b_emb, s_emb, dst, tab, deg);
    scan1_k<<<nbScan, 256, 0, stream>>>(deg, scanned, partials);
    scan2_k<<<1, 512, 0, stream>>>(partials, blockoff, nbScan);
    scan3_k<<<nbScan, 256, 0, stream>>>(scanned, blockoff, offs);
    fill_k<<<nbEdge, 256, 0, stream>>>(src, dst, offs, cursor, esrc);
    aggregate_k<<<nbNode4, 256, 0, stream>>>(tab, offs, esrc, out);
    gemm_mfma_k<<<dim3(nbTile, 3), 256, 0, stream>>>(out, W_e, b_e, W_b, b_b, W_s, b_s, deg);
}

// Round 2
// 638.851 us; speedup vs baseline: 1.1960x; 1.0025x over previous
//
#include <hip/hip_runtime.h>
#include <math.h>

#define N_NODESC 100000
#define N_EDGESC 1600000
#define DIMC 128
#define EPSV 1e-12f

typedef __attribute__((ext_vector_type(8))) short short8;
typedef __attribute__((ext_vector_type(4))) float f32x4;

// ---- bf16 helpers (round-to-nearest-even), packed 2 per uint ----
__device__ inline unsigned bf16r(float f) {
    unsigned u = __float_as_uint(f);
    return (u + 0x7FFFu + ((u >> 16) & 1u)) >> 16;
}
__device__ inline unsigned pack2(float lo, float hi) {
    return bf16r(lo) | (bf16r(hi) << 16);
}
__device__ inline float unlo(unsigned u) { return __uint_as_float(u << 16); }
__device__ inline float unhi(unsigned u) { return __uint_as_float(u & 0xFFFF0000u); }

// split f into hi/lo bf16 parts: f ~= hi + lo, |err| ~ 2^-17 * |f|
__device__ inline void bfsplit(float f, unsigned& h, unsigned& l) {
    h = bf16r(f);
    float fh = __uint_as_float(h << 16);
    l = bf16r(f - fh);
}

// ---------------- per-node pretransform -> interleaved bf16 gather table,
// with edge histogram fused in (25000 blocks x 64 edges = 1.6M exactly).
__global__ void pretransform_k(const float* __restrict__ e_emb,
                               const float* __restrict__ b_emb,
                               const float* __restrict__ s_emb,
                               const int* __restrict__ dst,
                               unsigned* __restrict__ tab,
                               int* __restrict__ deg) {
    // fused histogram: fire-and-forget atomics, no dependency on node work
    {
        int e = blockIdx.x * 64 + threadIdx.x;
        if (threadIdx.x < 64 && e < N_EDGESC) atomicAdd(&deg[dst[e]], 1);
    }
    int wave = (blockIdx.x * blockDim.x + threadIdx.x) >> 6;
    int lane = threadIdx.x & 63;
    if (wave >= N_NODESC) return;
    float2 ev = ((const float2*)(e_emb + (size_t)wave * DIMC))[lane];
    float2 bv = ((const float2*)(b_emb + (size_t)wave * DIMC))[lane];
    float2 sv = ((const float2*)(s_emb + (size_t)wave * DIMC))[lane];
    float bss = bv.x * bv.x + bv.y * bv.y;
    float sss = sv.x * sv.x + sv.y * sv.y;
    #pragma unroll
    for (int m = 1; m < 64; m <<= 1) {
        bss += __shfl_xor(bss, m, 64);
        sss += __shfl_xor(sss, m, 64);
    }
    float bn  = sqrtf(bss);
    float bns = fmaxf(bn, EPSV);
    float bcl = fminf(fmaxf(bns, EPSV), 1.0f - 1e-5f);
    float bsc = atanhf(bcl) / bns;
    float sn  = sqrtf(sss);
    float ssc = 1.0f / fmaxf(sn, EPSV);
    unsigned* p = tab + (size_t)wave * 192 + lane * 3;
    uint3 v;
    v.x = pack2(ev.x, ev.y);
    v.y = pack2(bv.x * bsc, bv.y * bsc);
    v.z = pack2(sv.x * ssc, sv.y * ssc);
    *(uint3*)p = v;
}

// ---------------- CSR build: two-level scan, fill
__global__ void scan1_k(const int* __restrict__ deg, int* __restrict__ scanned,
                        int* __restrict__ partials) {
    __shared__ int s[256];
    int t = threadIdx.x;
    int g = blockIdx.x * 256 + t;
    int v = (g < N_NODESC) ? deg[g] : 0;
    s[t] = v;
    __syncthreads();
    for (int off = 1; off < 256; off <<= 1) {
        int x = (t >= off) ? s[t - off] : 0;
        __syncthreads();
        s[t] += x;
        __syncthreads();
    }
    if (g < N_NODESC) scanned[g] = s[t];
    if (t == 255) partials[blockIdx.x] = s[255];
}

__global__ void scan2_k(const int* __restrict__ partials, int* __restrict__ blockoff, int nb) {
    __shared__ int s[512];
    int t = threadIdx.x;
    int v = (t < nb) ? partials[t] : 0;
    s[t] = v;
    __syncthreads();
    for (int off = 1; off < 512; off <<= 1) {
        int x = (t >= off) ? s[t - off] : 0;
        __syncthreads();
        s[t] += x;
        __syncthreads();
    }
    if (t < nb) blockoff[t] = s[t] - v;  // exclusive
}

__global__ void scan3_k(const int* __restrict__ scanned, const int* __restrict__ blockoff,
                        int* __restrict__ offs) {
    int g = blockIdx.x * 256 + threadIdx.x;
    if (g < N_NODESC) offs[g + 1] = scanned[g] + blockoff[blockIdx.x];
    if (g == 0) offs[0] = 0;
}

__global__ void fill_k(const int* __restrict__ src, const int* __restrict__ dst,
                       const int* __restrict__ offs, int* __restrict__ cursor,
                       int* __restrict__ esrc) {
    int e = blockIdx.x * 256 + threadIdx.x;
    if (e < N_EDGESC) {
        int d = dst[e];
        int pos = offs[d] + atomicAdd(&cursor[d], 1);
        esrc[pos] = src[e];
    }
}

// ---------------- aggregation: one wave per node, gather bf16 interleaved table.
// 4-edge unroll (4 independent 12B gathers in flight). Index loads are hoisted
// to the scalar pipe via readfirstlane(j): j is wave-uniform, so esrc[js..]
// become s_load through the K$ — VMEM pipe is left entirely to the gathers.
// (Round-1 lesson: nontemporal hints on esrc cost +17MB refetch and serialized
// index loads onto VMEM — reverted.)
__global__ void aggregate_k(const unsigned* __restrict__ tab,
                            const int* __restrict__ offs,
                            const int* __restrict__ esrc,
                            float* __restrict__ out) {
    int wave = (blockIdx.x * blockDim.x + threadIdx.x) >> 6;
    int lane = threadIdx.x & 63;
    if (wave >= N_NODESC) return;
    int beg = offs[wave], end = offs[wave + 1];
    float ae0 = 0.f, ae1 = 0.f, ab0 = 0.f, ab1 = 0.f, as0 = 0.f, as1 = 0.f;
    int lo3 = lane * 3;
    int j = beg;
    for (; j + 3 < end; j += 4) {
        int js = __builtin_amdgcn_readfirstlane(j);
        int s0 = esrc[js + 0];
        int s1 = esrc[js + 1];
        int s2 = esrc[js + 2];
        int s3 = esrc[js + 3];
        uint3 v0 = *(const uint3*)(tab + (size_t)s0 * 192 + lo3);
        uint3 v1 = *(const uint3*)(tab + (size_t)s1 * 192 + lo3);
        uint3 v2 = *(const uint3*)(tab + (size_t)s2 * 192 + lo3);
        uint3 v3 = *(const uint3*)(tab + (size_t)s3 * 192 + lo3);
        ae0 += (unlo(v0.x) + unlo(v1.x)) + (unlo(v2.x) + unlo(v3.x));
        ae1 += (unhi(v0.x) + unhi(v1.x)) + (unhi(v2.x) + unhi(v3.x));
        ab0 += (unlo(v0.y) + unlo(v1.y)) + (unlo(v2.y) + unlo(v3.y));
        ab1 += (unhi(v0.y) + unhi(v1.y)) + (unhi(v2.y) + unhi(v3.y));
        as0 += (unlo(v0.z) + unlo(v1.z)) + (unlo(v2.z) + unlo(v3.z));
        as1 += (unhi(v0.z) + unhi(v1.z)) + (unhi(v2.z) + unhi(v3.z));
    }
    if (j + 1 < end) {
        int js = __builtin_amdgcn_readfirstlane(j);
        int s0 = esrc[js + 0];
        int s1 = esrc[js + 1];
        uint3 v0 = *(const uint3*)(tab + (size_t)s0 * 192 + lo3);
        uint3 v1 = *(const uint3*)(tab + (size_t)s1 * 192 + lo3);
        ae0 += unlo(v0.x) + unlo(v1.x);
        ae1 += unhi(v0.x) + unhi(v1.x);
        ab0 += unlo(v0.y) + unlo(v1.y);
        ab1 += unhi(v0.y) + unhi(v1.y);
        as0 += unlo(v0.z) + unlo(v1.z);
        as1 += unhi(v0.z) + unhi(v1.z);
        j += 2;
    }
    if (j < end) {
        int js = __builtin_amdgcn_readfirstlane(j);
        int s0 = esrc[js];
        uint3 v0 = *(const uint3*)(tab + (size_t)s0 * 192 + lo3);
        ae0 += unlo(v0.x); ae1 += unhi(v0.x);
        ab0 += unlo(v0.y); ab1 += unhi(v0.y);
        as0 += unlo(v0.z); as1 += unhi(v0.z);
    }
    int deg = end - beg;
    float inv = (deg > 0) ? 1.0f / (float)deg : 0.0f;
    ((float2*)(out + (size_t)wave * DIMC))[lane]                           = make_float2(ae0 * inv, ae1 * inv);
    ((float2*)(out + (size_t)(N_NODESC + wave) * DIMC))[lane]              = make_float2(ab0 * inv, ab1 * inv);
    ((float2*)(out + (size_t)(2 * (size_t)N_NODESC + wave) * DIMC))[lane]  = make_float2(as0 * inv, as1 * inv);
}

// ---------------- fused GEMM via MFMA with bf16 hi/lo split (fp32-accurate):
// C = A@W^T + b, A fp32 in-place in `out`. Per product: Ah*Wh + Al*Wh + Ah*Wl,
// error ~2^-17 relative -> numerically equivalent to the fp32 VALU version,
// but runs on the matrix pipe instead of saturating VALU issue.
// Block: 256 thr = 4 waves, tile 64 rows x 128 cols, K split in 2 halves of 64.
// W staged per-half in LDS as bf16 hi/lo, [128][72] pad (144B row = 16B-aligned,
// 2-way bank alias only).
__global__ __launch_bounds__(256, 2) void gemm_mfma_k(
    float* __restrict__ out,
    const float* __restrict__ W_e, const float* __restrict__ b_e,
    const float* __restrict__ W_b, const float* __restrict__ b_b,
    const float* __restrict__ W_s, const float* __restrict__ b_s,
    const int* __restrict__ deg) {
    __shared__ unsigned short Wh[128][72];
    __shared__ unsigned short Wl[128][72];
    int c = blockIdx.y;
    const float* W    = (c == 0) ? W_e : (c == 1) ? W_b : W_s;
    const float* bias = (c == 0) ? b_e : (c == 1) ? b_b : b_s;
    float* A = out + (size_t)c * N_NODESC * DIMC;

    int tid = threadIdx.x;
    int wid = tid >> 6, lane = tid & 63;
    int m0 = blockIdx.x * 64;
    // A-fragment addressing: row = lane&15, k-chunk by lane>>4 (8 contiguous k).
    int arow = m0 + wid * 16 + (lane & 15);
    int kb = (lane >> 4) * 8;
    bool rowok = (arow < N_NODESC);
    const float* Ap = A + (size_t)arow * DIMC + kb;
    int colw = lane & 15;

    f32x4 acc[8] = {};

    for (int h = 0; h < 2; ++h) {
        // ---- A fragments for this K-half (global -> reg, fp32 -> bf16 hi/lo)
        short8 Ah[2], Al[2];
        #pragma unroll
        for (int ks = 0; ks < 2; ++ks) {
            float4 a0 = make_float4(0.f, 0.f, 0.f, 0.f);
            float4 a1 = a0;
            if (rowok) {
                a0 = *(const float4*)(Ap + h * 64 + ks * 32);
                a1 = *(const float4*)(Ap + h * 64 + ks * 32 + 4);
            }
            #define SPLIT8(val, idx) { unsigned hh, ll; bfsplit(val, hh, ll); \
                Ah[ks][idx] = (short)hh; Al[ks][idx] = (short)ll; }
            SPLIT8(a0.x, 0) SPLIT8(a0.y, 1) SPLIT8(a0.z, 2) SPLIT8(a0.w, 3)
            SPLIT8(a1.x, 4) SPLIT8(a1.y, 5) SPLIT8(a1.z, 6) SPLIT8(a1.w, 7)
            #undef SPLIT8
        }
        // ---- stage W K-half into LDS as hi/lo bf16
        if (h) __syncthreads();   // previous half's reads done before overwrite
        #pragma unroll
        for (int r = 0; r < 8; ++r) {
            int flat = (r * 256 + tid) * 4;      // float index within half
            int n  = flat >> 6;                  // 64 floats per row-half
            int kk = flat & 63;
            float4 w4 = *(const float4*)(W + (size_t)n * DIMC + h * 64 + kk);
            unsigned h0, h1, h2, h3, l0, l1, l2, l3;
            bfsplit(w4.x, h0, l0); bfsplit(w4.y, h1, l1);
            bfsplit(w4.z, h2, l2); bfsplit(w4.w, h3, l3);
            *(uint2*)&Wh[n][kk] = make_uint2(h0 | (h1 << 16), h2 | (h3 << 16));
            *(uint2*)&Wl[n][kk] = make_uint2(l0 | (l1 << 16), l2 | (l3 << 16));
        }
        __syncthreads();
        // ---- MFMA: 8 col-groups x 2 k-steps x 3 split terms
        #pragma unroll
        for (int n = 0; n < 8; ++n) {
            int col = n * 16 + colw;
            #pragma unroll
            for (int ks = 0; ks < 2; ++ks) {
                short8 wh = *(const short8*)&Wh[col][ks * 32 + kb];
                short8 wl = *(const short8*)&Wl[col][ks * 32 + kb];
                acc[n] = __builtin_amdgcn_mfma_f32_16x16x32_bf16(Ah[ks], wh, acc[n], 0, 0, 0);
                acc[n] = __builtin_amdgcn_mfma_f32_16x16x32_bf16(Al[ks], wh, acc[n], 0, 0, 0);
                acc[n] = __builtin_amdgcn_mfma_f32_16x16x32_bf16(Ah[ks], wl, acc[n], 0, 0, 0);
            }
        }
    }

    // ---- epilogue. C/D layout: col = lane&15 (within n-group), row = (lane>>4)*4 + reg
    int r0 = m0 + wid * 16 + (lane >> 4) * 4;
    float bn[8];
    #pragma unroll
    for (int n = 0; n < 8; ++n) bn[n] = bias[n * 16 + colw];

    if (c == 0) {
        #pragma unroll
        for (int rg = 0; rg < 4; ++rg) {
            int row = r0 + rg;
            if (row >= N_NODESC) continue;
            float* Ar = A + (size_t)row * DIMC;
            #pragma unroll
            for (int n = 0; n < 8; ++n) {
                float z = acc[n][rg] + bn[n];
                Ar[n * 16 + colw] = (z >= 0.f) ? z : 0.2f * z;
            }
        }
    } else {
        #pragma unroll
        for (int rg = 0; rg < 4; ++rg) {
            float z[8];
            float ss = 0.f;
            #pragma unroll
            for (int n = 0; n < 8; ++n) {
                z[n] = acc[n][rg] + bn[n];
                ss += z[n] * z[n];
            }
            // row's 128 cols live in the 16 lanes sharing lane>>4: reduce over bits 0..3
            ss += __shfl_xor(ss, 1, 64);
            ss += __shfl_xor(ss, 2, 64);
            ss += __shfl_xor(ss, 4, 64);
            ss += __shfl_xor(ss, 8, 64);
            float nrm = sqrtf(ss);
            float scale;
            if (c == 1) {
                float nsafe = fmaxf(nrm, EPSV);
                scale = tanhf(nsafe) / nsafe;       // expmap0
            } else {
                scale = 1.0f / fmaxf(nrm, EPSV);    // l2_normalize
            }
            int row = r0 + rg;
            if (row < N_NODESC) {
                if (deg[row] <= 0) scale = 0.0f;
                float* Ar = A + (size_t)row * DIMC;
                #pragma unroll
                for (int n = 0; n < 8; ++n) Ar[n * 16 + colw] = z[n] * scale;
            }
        }
    }
}

extern "C" void kernel_launch(void* const* d_in, const int* in_sizes, int n_in,
                              void* d_out, int out_size, void* d_ws, size_t ws_size,
                              hipStream_t stream) {
    const float* e_emb = (const float*)d_in[0];
    const float* b_emb = (const float*)d_in[1];
    const float* s_emb = (const float*)d_in[2];
    const float* W_e   = (const float*)d_in[3];
    const float* b_e   = (const float*)d_in[4];
    const float* W_b   = (const float*)d_in[5];
    const float* b_b   = (const float*)d_in[6];
    const float* W_s   = (const float*)d_in[7];
    const float* b_s   = (const float*)d_in[8];
    const int*   src   = (const int*)d_in[9];
    const int*   dst   = (const int*)d_in[10];
    float* out = (float*)d_out;

    // workspace layout
    char* w = (char*)d_ws;
    unsigned* tab = (unsigned*)w; w += (size_t)N_NODESC * 192 * sizeof(unsigned);  // 76.8 MB
    int* deg      = (int*)w;   w += (size_t)N_NODESC * sizeof(int);
    int* cursor   = (int*)w;   w += (size_t)N_NODESC * sizeof(int);
    int* scanned  = (int*)w;   w += (size_t)N_NODESC * sizeof(int);
    int* partials = (int*)w;   w += 512 * sizeof(int);
    int* blockoff = (int*)w;   w += 512 * sizeof(int);
    int* offs     = (int*)w;   w += (size_t)(N_NODESC + 1) * sizeof(int);
    w = (char*)(((uintptr_t)w + 255) & ~(uintptr_t)255);
    int* esrc     = (int*)w;   w += (size_t)N_EDGESC * sizeof(int);

    const int nbScan  = (N_NODESC + 255) / 256;   // 391
    const int nbEdge  = (N_EDGESC + 255) / 256;   // 6250
    const int nbNode4 = (N_NODESC + 3) / 4;       // 25000
    const int nbTile  = (N_NODESC + 63) / 64;     // 1563

    hipMemsetAsync(deg, 0, (size_t)2 * N_NODESC * sizeof(int), stream);

    pretransform_k<<<nbNode4, 256, 0, stream>>>(e_emb, b_emb, s_emb, dst, tab, deg);
    scan1_k<<<nbScan, 256, 0, stream>>>(deg, scanned, partials);
    scan2_k<<<1, 512, 0, stream>>>(partials, blockoff, nbScan);
    scan3_k<<<nbScan, 256, 0, stream>>>(scanned, blockoff, offs);
    fill_k<<<nbEdge, 256, 0, stream>>>(src, dst, offs, cursor, esrc);
    aggregate_k<<<nbNode4, 256, 0, stream>>>(tab, offs, esrc, out);
    gemm_mfma_k<<<dim3(nbTile, 3), 256, 0, stream>>>(out, W_e, b_e, W_b, b_b, W_s, b_s, deg);
}

// Round 3
// 632.917 us; speedup vs baseline: 1.2072x; 1.0094x over previous
//
#include <hip/hip_runtime.h>
#include <math.h>

#define N_NODESC 100000
#define N_EDGESC 1600000
#define DIMC 128
#define EPSV 1e-12f

typedef __attribute__((ext_vector_type(8))) short short8;
typedef __attribute__((ext_vector_type(4))) float f32x4;
typedef __attribute__((ext_vector_type(2))) float f32x2;

// ---- bf16 helpers (round-to-nearest-even), packed 2 per uint ----
__device__ inline unsigned bf16r(float f) {
    unsigned u = __float_as_uint(f);
    return (u + 0x7FFFu + ((u >> 16) & 1u)) >> 16;
}
__device__ inline unsigned pack2(float lo, float hi) {
    return bf16r(lo) | (bf16r(hi) << 16);
}
__device__ inline float unlo(unsigned u) { return __uint_as_float(u << 16); }
__device__ inline float unhi(unsigned u) { return __uint_as_float(u & 0xFFFF0000u); }

// split f into hi/lo bf16 parts: f ~= hi + lo, |err| ~ 2^-17 * |f|
__device__ inline void bfsplit(float f, unsigned& h, unsigned& l) {
    h = bf16r(f);
    float fh = __uint_as_float(h << 16);
    l = bf16r(f - fh);
}

// ---------------- per-node pretransform -> interleaved bf16 gather table,
// with edge histogram fused in (25000 blocks x 64 edges = 1.6M exactly).
// Inputs are read-once streams -> nontemporal loads so they don't evict the
// gather table (written here, reused heavily by aggregate_k) from L3.
__global__ void pretransform_k(const float* __restrict__ e_emb,
                               const float* __restrict__ b_emb,
                               const float* __restrict__ s_emb,
                               const int* __restrict__ dst,
                               unsigned* __restrict__ tab,
                               int* __restrict__ deg) {
    // fused histogram: fire-and-forget atomics, no dependency on node work
    {
        int e = blockIdx.x * 64 + threadIdx.x;
        if (threadIdx.x < 64 && e < N_EDGESC) atomicAdd(&deg[dst[e]], 1);
    }
    int wave = (blockIdx.x * blockDim.x + threadIdx.x) >> 6;
    int lane = threadIdx.x & 63;
    if (wave >= N_NODESC) return;
    f32x2 ev = __builtin_nontemporal_load((const f32x2*)(e_emb + (size_t)wave * DIMC) + lane);
    f32x2 bv = __builtin_nontemporal_load((const f32x2*)(b_emb + (size_t)wave * DIMC) + lane);
    f32x2 sv = __builtin_nontemporal_load((const f32x2*)(s_emb + (size_t)wave * DIMC) + lane);
    float bss = bv.x * bv.x + bv.y * bv.y;
    float sss = sv.x * sv.x + sv.y * sv.y;
    #pragma unroll
    for (int m = 1; m < 64; m <<= 1) {
        bss += __shfl_xor(bss, m, 64);
        sss += __shfl_xor(sss, m, 64);
    }
    float bn  = sqrtf(bss);
    float bns = fmaxf(bn, EPSV);
    float bcl = fminf(fmaxf(bns, EPSV), 1.0f - 1e-5f);
    float bsc = atanhf(bcl) / bns;
    float sn  = sqrtf(sss);
    float ssc = 1.0f / fmaxf(sn, EPSV);
    unsigned* p = tab + (size_t)wave * 192 + lane * 3;
    uint3 v;
    v.x = pack2(ev.x, ev.y);
    v.y = pack2(bv.x * bsc, bv.y * bsc);
    v.z = pack2(sv.x * ssc, sv.y * ssc);
    *(uint3*)p = v;
}

// ---------------- CSR build: two-level scan, fill
__global__ void scan1_k(const int* __restrict__ deg, int* __restrict__ scanned,
                        int* __restrict__ partials) {
    __shared__ int s[256];
    int t = threadIdx.x;
    int g = blockIdx.x * 256 + t;
    int v = (g < N_NODESC) ? deg[g] : 0;
    s[t] = v;
    __syncthreads();
    for (int off = 1; off < 256; off <<= 1) {
        int x = (t >= off) ? s[t - off] : 0;
        __syncthreads();
        s[t] += x;
        __syncthreads();
    }
    if (g < N_NODESC) scanned[g] = s[t];
    if (t == 255) partials[blockIdx.x] = s[255];
}

__global__ void scan2_k(const int* __restrict__ partials, int* __restrict__ blockoff, int nb) {
    __shared__ int s[512];
    int t = threadIdx.x;
    int v = (t < nb) ? partials[t] : 0;
    s[t] = v;
    __syncthreads();
    for (int off = 1; off < 512; off <<= 1) {
        int x = (t >= off) ? s[t - off] : 0;
        __syncthreads();
        s[t] += x;
        __syncthreads();
    }
    if (t < nb) blockoff[t] = s[t] - v;  // exclusive
}

__global__ void scan3_k(const int* __restrict__ scanned, const int* __restrict__ blockoff,
                        int* __restrict__ offs) {
    int g = blockIdx.x * 256 + threadIdx.x;
    if (g < N_NODESC) offs[g + 1] = scanned[g] + blockoff[blockIdx.x];
    if (g == 0) offs[0] = 0;
}

__global__ void fill_k(const int* __restrict__ src, const int* __restrict__ dst,
                       const int* __restrict__ offs, int* __restrict__ cursor,
                       int* __restrict__ esrc) {
    int e = blockIdx.x * 256 + threadIdx.x;
    if (e < N_EDGESC) {
        int d = __builtin_nontemporal_load(dst + e);   // last use of dst
        int sv = __builtin_nontemporal_load(src + e);  // only use of src
        int pos = offs[d] + atomicAdd(&cursor[d], 1);
        esrc[pos] = sv;                                // cached: re-read by aggregate
    }
}

// ---------------- aggregation: one wave per node, gather bf16 interleaved table.
// Per edge, lane loads one uint3 (12 B) = 2 dims x 3 channels. Accumulate fp32.
// ROUND-0 STRUCTURE (2-edge, 177us): rounds 1-2 showed deeper unroll/MLP HURTS
// (192us both) -> this kernel is L2-miss-path bandwidth-bound, not latency-bound.
__global__ void aggregate_k(const unsigned* __restrict__ tab,
                            const int* __restrict__ offs,
                            const int* __restrict__ esrc,
                            float* __restrict__ out) {
    int wave = (blockIdx.x * blockDim.x + threadIdx.x) >> 6;
    int lane = threadIdx.x & 63;
    if (wave >= N_NODESC) return;
    int beg = offs[wave], end = offs[wave + 1];
    float ae0 = 0.f, ae1 = 0.f, ab0 = 0.f, ab1 = 0.f, as0 = 0.f, as1 = 0.f;
    int j = beg;
    int lo3 = lane * 3;
    for (; j + 1 < end; j += 2) {
        int s0 = esrc[j], s1 = esrc[j + 1];
        uint3 v0 = *(const uint3*)(tab + (size_t)s0 * 192 + lo3);
        uint3 v1 = *(const uint3*)(tab + (size_t)s1 * 192 + lo3);
        ae0 += unlo(v0.x); ae1 += unhi(v0.x);
        ab0 += unlo(v0.y); ab1 += unhi(v0.y);
        as0 += unlo(v0.z); as1 += unhi(v0.z);
        ae0 += unlo(v1.x); ae1 += unhi(v1.x);
        ab0 += unlo(v1.y); ab1 += unhi(v1.y);
        as0 += unlo(v1.z); as1 += unhi(v1.z);
    }
    if (j < end) {
        int s0 = esrc[j];
        uint3 v0 = *(const uint3*)(tab + (size_t)s0 * 192 + lo3);
        ae0 += unlo(v0.x); ae1 += unhi(v0.x);
        ab0 += unlo(v0.y); ab1 += unhi(v0.y);
        as0 += unlo(v0.z); as1 += unhi(v0.z);
    }
    int deg = end - beg;
    float inv = (deg > 0) ? 1.0f / (float)deg : 0.0f;
    ((float2*)(out + (size_t)wave * DIMC))[lane]                           = make_float2(ae0 * inv, ae1 * inv);
    ((float2*)(out + (size_t)(N_NODESC + wave) * DIMC))[lane]              = make_float2(ab0 * inv, ab1 * inv);
    ((float2*)(out + (size_t)(2 * (size_t)N_NODESC + wave) * DIMC))[lane]  = make_float2(as0 * inv, as1 * inv);
}

// ---------------- fused GEMM via MFMA with bf16 hi/lo split (fp32-accurate):
// C = A@W^T + b, A fp32 in-place in `out`. Per product: Ah*Wh + Al*Wh + Ah*Wl,
// error ~2^-17 relative -> numerically equivalent to the fp32 VALU version,
// but runs on the matrix pipe instead of saturating VALU issue.
// Block: 256 thr = 4 waves, tile 64 rows x 128 cols, K split in 2 halves of 64.
// W staged per-half in LDS as bf16 hi/lo, [128][72] pad.
// Final stores are nontemporal: output is never re-read on device.
__global__ __launch_bounds__(256, 2) void gemm_mfma_k(
    float* __restrict__ out,
    const float* __restrict__ W_e, const float* __restrict__ b_e,
    const float* __restrict__ W_b, const float* __restrict__ b_b,
    const float* __restrict__ W_s, const float* __restrict__ b_s,
    const int* __restrict__ deg) {
    __shared__ unsigned short Wh[128][72];
    __shared__ unsigned short Wl[128][72];
    int c = blockIdx.y;
    const float* W    = (c == 0) ? W_e : (c == 1) ? W_b : W_s;
    const float* bias = (c == 0) ? b_e : (c == 1) ? b_b : b_s;
    float* A = out + (size_t)c * N_NODESC * DIMC;

    int tid = threadIdx.x;
    int wid = tid >> 6, lane = tid & 63;
    int m0 = blockIdx.x * 64;
    // A-fragment addressing: row = lane&15, k-chunk by lane>>4 (8 contiguous k).
    int arow = m0 + wid * 16 + (lane & 15);
    int kb = (lane >> 4) * 8;
    bool rowok = (arow < N_NODESC);
    const float* Ap = A + (size_t)arow * DIMC + kb;
    int colw = lane & 15;

    f32x4 acc[8] = {};

    for (int h = 0; h < 2; ++h) {
        // ---- A fragments for this K-half (global -> reg, fp32 -> bf16 hi/lo)
        short8 Ah[2], Al[2];
        #pragma unroll
        for (int ks = 0; ks < 2; ++ks) {
            float4 a0 = make_float4(0.f, 0.f, 0.f, 0.f);
            float4 a1 = a0;
            if (rowok) {
                a0 = *(const float4*)(Ap + h * 64 + ks * 32);
                a1 = *(const float4*)(Ap + h * 64 + ks * 32 + 4);
            }
            #define SPLIT8(val, idx) { unsigned hh, ll; bfsplit(val, hh, ll); \
                Ah[ks][idx] = (short)hh; Al[ks][idx] = (short)ll; }
            SPLIT8(a0.x, 0) SPLIT8(a0.y, 1) SPLIT8(a0.z, 2) SPLIT8(a0.w, 3)
            SPLIT8(a1.x, 4) SPLIT8(a1.y, 5) SPLIT8(a1.z, 6) SPLIT8(a1.w, 7)
            #undef SPLIT8
        }
        // ---- stage W K-half into LDS as hi/lo bf16
        if (h) __syncthreads();   // previous half's reads done before overwrite
        #pragma unroll
        for (int r = 0; r < 8; ++r) {
            int flat = (r * 256 + tid) * 4;      // float index within half
            int n  = flat >> 6;                  // 64 floats per row-half
            int kk = flat & 63;
            float4 w4 = *(const float4*)(W + (size_t)n * DIMC + h * 64 + kk);
            unsigned h0, h1, h2, h3, l0, l1, l2, l3;
            bfsplit(w4.x, h0, l0); bfsplit(w4.y, h1, l1);
            bfsplit(w4.z, h2, l2); bfsplit(w4.w, h3, l3);
            *(uint2*)&Wh[n][kk] = make_uint2(h0 | (h1 << 16), h2 | (h3 << 16));
            *(uint2*)&Wl[n][kk] = make_uint2(l0 | (l1 << 16), l2 | (l3 << 16));
        }
        __syncthreads();
        // ---- MFMA: 8 col-groups x 2 k-steps x 3 split terms
        #pragma unroll
        for (int n = 0; n < 8; ++n) {
            int col = n * 16 + colw;
            #pragma unroll
            for (int ks = 0; ks < 2; ++ks) {
                short8 wh = *(const short8*)&Wh[col][ks * 32 + kb];
                short8 wl = *(const short8*)&Wl[col][ks * 32 + kb];
                acc[n] = __builtin_amdgcn_mfma_f32_16x16x32_bf16(Ah[ks], wh, acc[n], 0, 0, 0);
                acc[n] = __builtin_amdgcn_mfma_f32_16x16x32_bf16(Al[ks], wh, acc[n], 0, 0, 0);
                acc[n] = __builtin_amdgcn_mfma_f32_16x16x32_bf16(Ah[ks], wl, acc[n], 0, 0, 0);
            }
        }
    }

    // ---- epilogue. C/D layout: col = lane&15 (within n-group), row = (lane>>4)*4 + reg
    int r0 = m0 + wid * 16 + (lane >> 4) * 4;
    float bn[8];
    #pragma unroll
    for (int n = 0; n < 8; ++n) bn[n] = bias[n * 16 + colw];

    if (c == 0) {
        #pragma unroll
        for (int rg = 0; rg < 4; ++rg) {
            int row = r0 + rg;
            if (row >= N_NODESC) continue;
            float* Ar = A + (size_t)row * DIMC;
            #pragma unroll
            for (int n = 0; n < 8; ++n) {
                float z = acc[n][rg] + bn[n];
                float o = (z >= 0.f) ? z : 0.2f * z;
                __builtin_nontemporal_store(o, &Ar[n * 16 + colw]);
            }
        }
    } else {
        #pragma unroll
        for (int rg = 0; rg < 4; ++rg) {
            float z[8];
            float ss = 0.f;
            #pragma unroll
            for (int n = 0; n < 8; ++n) {
                z[n] = acc[n][rg] + bn[n];
                ss += z[n] * z[n];
            }
            // row's 128 cols live in the 16 lanes sharing lane>>4: reduce over bits 0..3
            ss += __shfl_xor(ss, 1, 64);
            ss += __shfl_xor(ss, 2, 64);
            ss += __shfl_xor(ss, 4, 64);
            ss += __shfl_xor(ss, 8, 64);
            float nrm = sqrtf(ss);
            float scale;
            if (c == 1) {
                float nsafe = fmaxf(nrm, EPSV);
                scale = tanhf(nsafe) / nsafe;       // expmap0
            } else {
                scale = 1.0f / fmaxf(nrm, EPSV);    // l2_normalize
            }
            int row = r0 + rg;
            if (row < N_NODESC) {
                if (deg[row] <= 0) scale = 0.0f;
                float* Ar = A + (size_t)row * DIMC;
                #pragma unroll
                for (int n = 0; n < 8; ++n)
                    __builtin_nontemporal_store(z[n] * scale, &Ar[n * 16 + colw]);
            }
        }
    }
}

extern "C" void kernel_launch(void* const* d_in, const int* in_sizes, int n_in,
                              void* d_out, int out_size, void* d_ws, size_t ws_size,
                              hipStream_t stream) {
    const float* e_emb = (const float*)d_in[0];
    const float* b_emb = (const float*)d_in[1];
    const float* s_emb = (const float*)d_in[2];
    const float* W_e   = (const float*)d_in[3];
    const float* b_e   = (const float*)d_in[4];
    const float* W_b   = (const float*)d_in[5];
    const float* b_b   = (const float*)d_in[6];
    const float* W_s   = (const float*)d_in[7];
    const float* b_s   = (const float*)d_in[8];
    const int*   src   = (const int*)d_in[9];
    const int*   dst   = (const int*)d_in[10];
    float* out = (float*)d_out;

    // workspace layout
    char* w = (char*)d_ws;
    unsigned* tab = (unsigned*)w; w += (size_t)N_NODESC * 192 * sizeof(unsigned);  // 76.8 MB
    int* deg      = (int*)w;   w += (size_t)N_NODESC * sizeof(int);
    int* cursor   = (int*)w;   w += (size_t)N_NODESC * sizeof(int);
    int* scanned  = (int*)w;   w += (size_t)N_NODESC * sizeof(int);
    int* partials = (int*)w;   w += 512 * sizeof(int);
    int* blockoff = (int*)w;   w += 512 * sizeof(int);
    int* offs     = (int*)w;   w += (size_t)(N_NODESC + 1) * sizeof(int);
    w = (char*)(((uintptr_t)w + 255) & ~(uintptr_t)255);
    int* esrc     = (int*)w;   w += (size_t)N_EDGESC * sizeof(int);

    const int nbScan  = (N_NODESC + 255) / 256;   // 391
    const int nbEdge  = (N_EDGESC + 255) / 256;   // 6250
    const int nbNode4 = (N_NODESC + 3) / 4;       // 25000
    const int nbTile  = (N_NODESC + 63) / 64;     // 1563

    hipMemsetAsync(deg, 0, (size_t)2 * N_NODESC * sizeof(int), stream);

    pretransform_k<<<nbNode4, 256, 0, stream>>>(e_emb, b_emb, s_emb, dst, tab, deg);
    scan1_k<<<nbScan, 256, 0, stream>>>(deg, scanned, partials);
    scan2_k<<<1, 512, 0, stream>>>(partials, blockoff, nbScan);
    scan3_k<<<nbScan, 256, 0, stream>>>(scanned, blockoff, offs);
    fill_k<<<nbEdge, 256, 0, stream>>>(src, dst, offs, cursor, esrc);
    aggregate_k<<<nbNode4, 256, 0, stream>>>(tab, offs, esrc, out);
    gemm_mfma_k<<<dim3(nbTile, 3), 256, 0, stream>>>(out, W_e, b_e, W_b, b_b, W_s, b_s, deg);
}